// Round 2
// baseline (255.639 us; speedup 1.0000x reference)
//
#include <hip/hip_runtime.h>
#include <math.h>

#define FIELD  39
#define NPF    38      // fields in the pairwise term (0..37)
#define NPAIRS 703     // C(38,2)
#define FEAT   100000
#define EMB    10

typedef float f4 __attribute__((ext_vector_type(4)));

// element e (0..11) of a 48B window held as 3 float4s; e must be a compile-time const
#define ELT(Q, e) ((e) < 4 ? (Q)[0][(e)] : (e) < 8 ? (Q)[1][(e)-4] : (Q)[2][(e)-8])

// closed-form pair decode: p -> (i,j), 0 <= i < j < 38
// off(i) = i*(75-i)/2 ; i = floor((75 - sqrt(75^2 - 8p))/2), corrected +-1
__device__ __forceinline__ void decode_pair(int p, int& i_out, int& j_out) {
    const float disc = 5625.0f - 8.0f * (float)p;
    int i = (int)((75.0f - sqrtf(disc)) * 0.5f);
    int off = (i * (75 - i)) >> 1;
    if (p < off) {
        --i; off = (i * (75 - i)) >> 1;
    } else {
        const int off1 = ((i + 1) * (74 - i)) >> 1;
        if (p >= off1) { ++i; off = off1; }
    }
    i_out = i;
    j_out = i + 1 + (p - off);
}

__global__ __launch_bounds__(256) void ffm_kernel(
    const int*   __restrict__ idxs,   // [B, 39]
    const float* __restrict__ vals,   // [B, 39]
    const float* __restrict__ emb,    // [39, 100000, 10]
    const float* __restrict__ w1,     // [100000, 1]
    float*       __restrict__ out)    // [B]
{
    const int b = blockIdx.x;
    const int t = threadIdx.x;

    __shared__ int   s_idx[FIELD];
    __shared__ float s_val[FIELD];
    if (t < FIELD) {
        s_idx[t] = idxs[b * FIELD + t];
        s_val[t] = vals[b * FIELD + t];
    }
    __syncthreads();

    // first-order term
    float acc = (t < FIELD) ? w1[s_idx[t]] * s_val[t] : 0.f;

    // ---- batched pairwise term: 3 pairs per thread, all loads issued first ----
    bool  valid[3];
    int   sha[3], shb[3];      // phase: row starts at +0 or +2 floats inside window
    float vv[3];
    const f4* pa[3];
    const f4* pb[3];

    #pragma unroll
    for (int k = 0; k < 3; ++k) {
        int p = t + (k << 8);
        valid[k] = (p < NPAIRS);
        p = valid[k] ? p : (NPAIRS - 1);
        int i, j;
        decode_pair(p, i, j);
        vv[k] = s_val[i] * s_val[j];

        const size_t byteA = ((size_t)i * FEAT + (size_t)s_idx[j]) * (EMB * 4); // 40B rows
        const size_t byteB = ((size_t)j * FEAT + (size_t)s_idx[i]) * (EMB * 4);
        sha[k] = (int)(byteA & 8) >> 2;   // 0 or 2 (float elements)
        shb[k] = (int)(byteB & 8) >> 2;
        pa[k] = (const f4*)((const char*)emb + (byteA & ~(size_t)15));
        pb[k] = (const f4*)((const char*)emb + (byteB & ~(size_t)15));
    }

    // issue all 18 dwordx4 loads back-to-back (max MLP)
    f4 A[3][3], B[3][3];
    #pragma unroll
    for (int k = 0; k < 3; ++k) {
        A[k][0] = pa[k][0]; A[k][1] = pa[k][1]; A[k][2] = pa[k][2];
        B[k][0] = pb[k][0]; B[k][1] = pb[k][1]; B[k][2] = pb[k][2];
    }

    // consume: phase-selected dot products
    #pragma unroll
    for (int k = 0; k < 3; ++k) {
        float s = 0.f;
        #pragma unroll
        for (int e = 0; e < EMB; ++e) {
            const float ae = sha[k] ? ELT(A[k], e + 2) : ELT(A[k], e);
            const float be = shb[k] ? ELT(B[k], e + 2) : ELT(B[k], e);
            s += ae * be;
        }
        acc += valid[k] ? s * vv[k] : 0.f;
    }

    // block reduction: wave64 shuffle, then 4 partials through LDS
    #pragma unroll
    for (int off = 32; off > 0; off >>= 1)
        acc += __shfl_down(acc, off, 64);

    __shared__ float wsum[4];
    if ((t & 63) == 0) wsum[t >> 6] = acc;
    __syncthreads();
    if (t == 0) {
        const float tot = wsum[0] + wsum[1] + wsum[2] + wsum[3];
        out[b] = 1.f / (1.f + expf(-tot));
    }
}

extern "C" void kernel_launch(void* const* d_in, const int* in_sizes, int n_in,
                              void* d_out, int out_size, void* d_ws, size_t ws_size,
                              hipStream_t stream) {
    const int*   idxs = (const int*)  d_in[0];   // [2048, 39] int32
    const float* vals = (const float*)d_in[1];   // [2048, 39] f32
    const float* emb  = (const float*)d_in[2];   // [39, 100000, 10] f32
    const float* w1   = (const float*)d_in[3];   // [100000, 1] f32
    float*       out  = (float*)d_out;           // [2048] f32

    ffm_kernel<<<out_size, 256, 0, stream>>>(idxs, vals, emb, w1, out);
}